// Round 6
// baseline (317.069 us; speedup 1.0000x reference)
//
#include <hip/hip_runtime.h>
#include <cstdint>
#include <cstddef>

#define NB 8
#define CIN 256
#define HWX 4096
#define CF 256
#define CA 128
#define CT 384

typedef __attribute__((ext_vector_type(8))) _Float16 half8;
typedef __attribute__((ext_vector_type(8))) short short8;
typedef __attribute__((ext_vector_type(4))) float f32x4;
typedef __attribute__((ext_vector_type(4))) unsigned int u32x4;
typedef __attribute__((ext_vector_type(2))) unsigned int u32x2;

// workspace layout (bytes)
#define OFF_WH   0                              // 384*256 fp16 folded weights
#define OFF_BIAS (CT*CIN*2)                     // 384 fp32 folded bias
#define OFF_FEAT (OFF_BIAS + CT*4)              // [n][256][4096] fp16
#define OFF_Q    (OFF_FEAT + NB*CF*HWX*2)       // [n][4096][128] fp16
#define OFF_NORM (OFF_Q + NB*HWX*CA*2)          // [n][4096] fp32 row norms of q
#define OFF_G    (OFF_NORM + NB*HWX*4)          // [n] uint (max norm bits)

__device__ inline unsigned short f16_bits(float f) {
  _Float16 h = (_Float16)f;
  return __builtin_bit_cast(unsigned short, h);
}
__device__ inline half8 ld_half8(const unsigned short* p) {
  short8 r = *(const short8*)p;
  return __builtin_bit_cast(half8, r);
}

// async global->LDS, 16B per lane; LDS side must be lane-linear (m104/m108),
// swizzle goes on the GLOBAL address.
__device__ inline void g2l16(const void* g, void* l) {
  __builtin_amdgcn_global_load_lds(
      (const __attribute__((address_space(1))) unsigned int*)g,
      (__attribute__((address_space(3))) unsigned int*)l, 16, 0, 0);
}

// ---------------- kernel 1: fold BN into fp16 weights (+ zero G) ----------------
__global__ __launch_bounds__(256) void fold_bn_k(
    const float* __restrict__ rw, const float* __restrict__ rg,
    const float* __restrict__ rb, const float* __restrict__ rm, const float* __restrict__ rv,
    const float* __restrict__ aw, const float* __restrict__ ag,
    const float* __restrict__ ab2, const float* __restrict__ am, const float* __restrict__ av,
    unsigned short* __restrict__ wh, float* __restrict__ bias, unsigned* __restrict__ Gmax) {
  int o = blockIdx.x, k = threadIdx.x;
  if (o == 0 && k < NB) Gmax[k] = 0u;
  const float* wsrc; float g, b, m, v;
  if (o < CF) { wsrc = rw + (size_t)o*CIN; g = rg[o]; b = rb[o]; m = rm[o]; v = rv[o]; }
  else { int oa = o - CF; wsrc = aw + (size_t)oa*CIN; g = ag[oa]; b = ab2[oa]; m = am[oa]; v = av[oa]; }
  float inv = g / sqrtf(v + 1e-5f);
  wh[(size_t)o*CIN + k] = f16_bits(wsrc[k] * inv);
  if (k == 0) bias[o] = b - m*inv;
}

// ---------------- kernel 2: fp16 MFMA conv(1x1)+BN+ReLU ----------------
// grid 1024 = 8n x 128 pos-tiles(32); 256 thr; 4+ blocks/CU.
// Block tile: [32 pos] x [384 oc] x K=256. Wave w owns oc slab [w*96, w*96+96).
// feat stores direct from regs; q round-trips LDS (transpose) + wave-reduced atomicMax.
__global__ __launch_bounds__(256, 4) void conv_k(
    const float* __restrict__ x, const unsigned short* __restrict__ wh,
    const float* __restrict__ bias, unsigned short* __restrict__ feat,
    unsigned short* __restrict__ q, float* __restrict__ normq,
    unsigned* __restrict__ Gmax) {
  __shared__ unsigned short sX[32*264];    // xT [32 pos][264] fp16, k-pairs packed
  __shared__ unsigned short sQr[32][136];  // qD [32 pos][128+8]
  int b = blockIdx.x;
  int n = b & 7, pt0 = b >> 3;
  int p0 = pt0 * 32;
  int t = threadIdx.x;
  int w = t >> 6, lane = t & 63, quad = lane >> 4, col = lane & 15;
  const float* xn = x + (size_t)n*CIN*HWX;

  // stage x tile [256 k][32 pos] -> LDS transposed fp16 [pos][k] (pairs packed)
  #pragma unroll
  for (int pass=0; pass<4; pass++) {
    int idx = pass*256 + t;
    int kp = idx >> 3, pl = idx & 7;
    f32x4 a = *(const f32x4*)(xn + (size_t)(2*kp)*HWX + p0 + pl*4);
    f32x4 c = *(const f32x4*)(xn + (size_t)(2*kp+1)*HWX + p0 + pl*4);
    #pragma unroll
    for (int j=0;j<4;j++) {
      int pos = pl*4 + j;
      unsigned dd = (unsigned)f16_bits(a[j]) | ((unsigned)f16_bits(c[j]) << 16);
      *(unsigned*)&sX[pos*264 + kp*2] = dd;
    }
  }
  __syncthreads();

  f32x4 fzero = {0.f,0.f,0.f,0.f};
  f32x4 acc[2][6];
  #pragma unroll
  for (int pt=0;pt<2;pt++)
    #pragma unroll
    for (int ot=0;ot<6;ot++) acc[pt][ot] = fzero;

  #pragma unroll
  for (int ks=0; ks<8; ks++) {
    half8 B6[6];
    #pragma unroll
    for (int ot=0;ot<6;ot++)
      B6[ot] = ld_half8(wh + (size_t)(w*96 + ot*16 + col)*CIN + ks*32 + quad*8);
    half8 A2[2];
    #pragma unroll
    for (int pt=0;pt<2;pt++)
      A2[pt] = ld_half8(&sX[(pt*16+col)*264 + ks*32 + quad*8]);
    #pragma unroll
    for (int pt=0;pt<2;pt++)
      #pragma unroll
      for (int ot=0;ot<6;ot++)
        acc[pt][ot] = __builtin_amdgcn_mfma_f32_16x16x32_f16(A2[pt], B6[ot], acc[pt][ot], 0, 0, 0);
  }

  // epilogue: bias+ReLU; feat (oc<256) straight to global; q (oc>=256) via LDS transpose
  float bv[6];
  #pragma unroll
  for (int ot=0;ot<6;ot++) bv[ot] = bias[w*96 + ot*16 + col];
  #pragma unroll
  for (int pt=0;pt<2;pt++)
    #pragma unroll
    for (int ot=0;ot<6;ot++) {
      int oc = w*96 + ot*16 + col;
      alignas(8) unsigned short u4[4];
      #pragma unroll
      for (int r=0;r<4;r++)
        u4[r] = f16_bits(fmaxf(acc[pt][ot][r] + bv[ot], 0.f));
      if (oc < CF) {
        // D frag: pos = pt*16+quad*4+r contiguous -> 8B store
        *(u32x2*)(feat + (size_t)n*CF*HWX + (size_t)oc*HWX + p0 + pt*16 + quad*4) =
            *(const u32x2*)u4;
      } else {
        int cc = oc - CF;
        #pragma unroll
        for (int r=0;r<4;r++)
          sQr[pt*16 + quad*4 + r][cc] = u4[r];
      }
    }
  __syncthreads();

  // q readback + row norms: t<128: pos=t>>2, seg=t&3 (32 c each)
  if (t < 128) {
    int pos = t >> 2, seg = t & 3;
    const unsigned short* src = &sQr[pos][seg*32];
    unsigned short* dst = q + ((size_t)n*HWX + p0 + pos)*CA + seg*32;
    float s2 = 0.f;
    #pragma unroll
    for (int u=0;u<4;u++) {
      short8 v = *(const short8*)(src + u*8);
      *(short8*)(dst + u*8) = v;
      half8 h = __builtin_bit_cast(half8, v);
      #pragma unroll
      for (int e=0;e<8;e++) { float fe = (float)h[e]; s2 += fe*fe; }
    }
    // butterfly over seg bits -> all lanes hold full |q_pos|^2
    s2 += __shfl_xor(s2, 1, 64);
    s2 += __shfl_xor(s2, 2, 64);
    if (seg == 0) normq[(size_t)n*HWX + p0 + pos] = sqrtf(s2);
    // wave max over remaining bits, ONE atomic per wave
    float mx = s2;
    mx = fmaxf(mx, __shfl_xor(mx, 4, 64));
    mx = fmaxf(mx, __shfl_xor(mx, 8, 64));
    mx = fmaxf(mx, __shfl_xor(mx, 16, 64));
    mx = fmaxf(mx, __shfl_xor(mx, 32, 64));
    if (lane == 0) atomicMax(Gmax + n, __float_as_uint(sqrtf(mx)));
  }
}

// ---------------- kernel 3: flash attention, single-barrier pipeline ----------------
// grid 512 = 8n x 64 i-tiles (BM=64); 512 thr (8 waves), 2 blocks/CU.
// Double-buffered sQ/sP/sM: between barriers a wave runs QK(ji)+softmax(ji) AND
// PV(ji-1) -- independent MFMA streams the scheduler interleaves; exp hides under PV.
// Wave (wq=w&3, wh=w>>2): QK owns rows wq*16, j-half wh; PV owns c-slab w*32.
// Max-free softmax via per-row Cauchy-Schwarz bound (R4).
__global__ __launch_bounds__(512, 4) void flash_k(
    const unsigned short* __restrict__ q, const unsigned short* __restrict__ feat,
    const float* __restrict__ mask, const float* __restrict__ normq,
    const unsigned* __restrict__ Gmax, float* __restrict__ out) {
  __shared__ alignas(16) unsigned short sQ[2][64*128];  // j-tile q fp16, octet-swizzled
  __shared__ alignas(16) unsigned short sP[2][64][72];  // P (A-layout), double-buffered
  __shared__ float sM[2][64];
  __shared__ float sL[2][64];
  int b = blockIdx.x;
  int n = b & 7, it = b >> 3;         // n == XCD for L2 locality
  int i0 = it * 64;
  int t = threadIdx.x;
  int w = t >> 6, lane = t & 63, quad = lane >> 4, col = lane & 15;
  int wq = w & 3, wh = w >> 2;
  const unsigned short* q_n = q + (size_t)n*HWX*CA;
  const unsigned short* f_n = feat + (size_t)n*CF*HWX;
  const float* m_n = mask + (size_t)n*HWX;
  const int rloc = (t >> 4) & 31, oct16 = t & 15;
  const float inv_s = 1.0f/(1e-8f + sqrtf(128.0f));

  auto stage_Q = [&](int ji, int buf) {
    int j0 = ji*64;
    #pragma unroll
    for (int c=0;c<2;c++) {
      int row = c*32 + rloc;
      int og = oct16 ^ (row & 15);
      g2l16(q_n + (size_t)(j0+row)*CA + og*8, &sQ[buf][(size_t)row*128 + oct16*8]);
    }
    if (t < 16) g2l16(m_n + j0 + t*4, &sM[buf][t*4]);
  };
  auto load_bF = [&](int ji, half8 (&bF)[2][2]) {
    int j0 = ji*64;
    #pragma unroll
    for (int ks2=0;ks2<2;ks2++)
      #pragma unroll
      for (int ct=0;ct<2;ct++) {
        int c = w*32 + ct*16 + col;
        bF[ks2][ct] = ld_half8(f_n + (size_t)c*HWX + j0 + ks2*32 + quad*8);
      }
  };

  // A fragments for QK (this wave's 16 i rows)
  half8 ah[4];
  {
    int arow = i0 + wq*16 + col;
    #pragma unroll
    for (int ks=0; ks<4; ks++)
      ah[ks] = ld_half8(q_n + (size_t)arow*CA + ks*32 + quad*8);
  }
  // per-row exp shift: C_i - 5
  float Gn = __uint_as_float(Gmax[n]);
  float cvals[4];
  #pragma unroll
  for (int r=0;r<4;r++)
    cvals[r] = normq[(size_t)n*HWX + i0 + wq*16 + quad*4 + r] * Gn * inv_s - 5.0f;

  f32x4 fzero = {0.f,0.f,0.f,0.f};
  f32x4 o[4][2];                      // [i-group][c-tile], c-slab = w*32
  #pragma unroll
  for (int ig=0;ig<4;ig++) { o[ig][0] = fzero; o[ig][1] = fzero; }
  float lrun[4] = {0.f,0.f,0.f,0.f};

  auto qk_softmax = [&](int buf) {
    f32x4 s[2];
    s[0] = fzero; s[1] = fzero;
    #pragma unroll
    for (int jt=0;jt<2;jt++) {
      int rowj = wh*32 + jt*16 + col;
      #pragma unroll
      for (int ks=0; ks<4; ks++) {
        int slot = (ks*4 + quad) ^ (rowj & 15);
        half8 bq = ld_half8(&sQ[buf][rowj*128 + slot*8]);
        s[jt] = __builtin_amdgcn_mfma_f32_16x16x32_f16(ah[ks], bq, s[jt], 0, 0, 0);
      }
    }
    #pragma unroll
    for (int jt=0;jt<2;jt++) {
      float mj = (sM[buf][wh*32 + jt*16 + col] - 1.f) * 1e8f;
      #pragma unroll
      for (int r=0;r<4;r++) {
        float p = __expf(s[jt][r]*inv_s + mj - cvals[r]);
        lrun[r] += p;
        sP[buf][wq*16 + quad*4 + r][wh*32 + jt*16 + col] = f16_bits(p);
      }
    }
  };
  auto do_PV = [&](int buf, half8 (&bF)[2][2]) {
    #pragma unroll
    for (int ks2=0; ks2<2; ks2++) {
      half8 aP[4];
      #pragma unroll
      for (int ig=0;ig<4;ig++)
        aP[ig] = ld_half8(&sP[buf][ig*16 + col][ks2*32 + quad*8]);
      #pragma unroll
      for (int ct=0;ct<2;ct++)
        #pragma unroll
        for (int ig=0;ig<4;ig++)
          o[ig][ct] = __builtin_amdgcn_mfma_f32_16x16x32_f16(aP[ig], bF[ks2][ct], o[ig][ct], 0, 0, 0);
    }
  };

  half8 bFa[2][2], bFb[2][2];
  // prologue
  stage_Q(0, 0);
  __syncthreads();                    // sQ[0]/sM[0] ready
  stage_Q(1, 1);
  load_bF(0, bFa);
  qk_softmax(0);                      // -> sP[0]

  #pragma unroll 1
  for (int jj = 0; jj < 31; jj++) {
    int ji = 2*jj + 1;
    __syncthreads();                  // sQ[1](ji) ready; sP[0](ji-1) visible; sP[1] free
    stage_Q(ji+1, 0);
    load_bF(ji, bFb);
    qk_softmax(1);                    // QK(ji) -> sP[1]
    do_PV(0, bFa);                    // PV(ji-1)
    __syncthreads();
    stage_Q(ji+2, 1);
    load_bF(ji+1, bFa);
    qk_softmax(0);                    // QK(ji+1) -> sP[0]
    do_PV(1, bFb);                    // PV(ji)
  }
  // after loop: QK done through 62, PV through 61; sQ[1] holds tile 63
  __syncthreads();
  load_bF(63, bFb);
  qk_softmax(1);                      // QK(63) -> sP[1]
  do_PV(0, bFa);                      // PV(62)
  __syncthreads();
  do_PV(1, bFb);                      // PV(63)

  // ---- final l: reduce 16 j-cols in-wave, combine halves via LDS
  #pragma unroll
  for (int r=0;r<4;r++) {
    float ss = lrun[r];
    ss += __shfl_xor(ss, 1, 64);
    ss += __shfl_xor(ss, 2, 64);
    ss += __shfl_xor(ss, 4, 64);
    ss += __shfl_xor(ss, 8, 64);
    lrun[r] = ss;
  }
  #pragma unroll
  for (int r=0;r<4;r++)
    if (col == 0) sL[wh][wq*16 + quad*4 + r] = lrun[r];
  __syncthreads();
  #pragma unroll
  for (int ig=0;ig<4;ig++) {
    int base = ig*16 + quad*4;
    f32x4 l0 = *(const f32x4*)&sL[0][base];
    f32x4 l1 = *(const f32x4*)&sL[1][base];
    f32x4 mv = *(const f32x4*)(m_n + i0 + base);
    f32x4 minv;
    #pragma unroll
    for (int r=0;r<4;r++) minv[r] = mv[r] / (l0[r] + l1[r]);
    #pragma unroll
    for (int ct=0;ct<2;ct++) {
      int c = w*32 + ct*16 + col;
      f32x4 v;
      #pragma unroll
      for (int r=0;r<4;r++) v[r] = o[ig][ct][r] * minv[r];
      *(f32x4*)(out + ((size_t)n*CF + c)*HWX + i0 + base) = v;
    }
  }
}

extern "C" void kernel_launch(void* const* d_in, const int* in_sizes, int n_in,
                              void* d_out, int out_size, void* d_ws, size_t ws_size,
                              hipStream_t stream) {
  const float* x    = (const float*)d_in[0];
  const float* mask = (const float*)d_in[1];
  const float* rw   = (const float*)d_in[2];
  const float* rg   = (const float*)d_in[3];
  const float* rb   = (const float*)d_in[4];
  const float* rm   = (const float*)d_in[5];
  const float* rv   = (const float*)d_in[6];
  const float* aw   = (const float*)d_in[7];
  const float* ag   = (const float*)d_in[8];
  const float* ab   = (const float*)d_in[9];
  const float* am   = (const float*)d_in[10];
  const float* av   = (const float*)d_in[11];
  float* out = (float*)d_out;
  char* ws = (char*)d_ws;
  unsigned short* wh = (unsigned short*)(ws + OFF_WH);
  float* bias = (float*)(ws + OFF_BIAS);
  unsigned short* feat = (unsigned short*)(ws + OFF_FEAT);
  unsigned short* q    = (unsigned short*)(ws + OFF_Q);
  float* normq = (float*)(ws + OFF_NORM);
  unsigned* Gmax = (unsigned*)(ws + OFF_G);

  hipLaunchKernelGGL(fold_bn_k, dim3(CT), dim3(CIN), 0, stream,
                     rw, rg, rb, rm, rv, aw, ag, ab, am, av, wh, bias, Gmax);
  hipLaunchKernelGGL(conv_k, dim3(1024), dim3(256), 0, stream,
                     x, wh, bias, feat, q, normq, Gmax);
  hipLaunchKernelGGL(flash_k, dim3(512), dim3(512), 0, stream,
                     q, feat, mask, normq, Gmax, out);
}

// Round 7
// 293.864 us; speedup vs baseline: 1.0790x; 1.0790x over previous
//
#include <hip/hip_runtime.h>
#include <cstdint>
#include <cstddef>

#define NB 8
#define CIN 256
#define HWX 4096
#define CF 256
#define CA 128
#define CT 384

typedef __attribute__((ext_vector_type(8))) _Float16 half8;
typedef __attribute__((ext_vector_type(8))) short short8;
typedef __attribute__((ext_vector_type(4))) float f32x4;
typedef __attribute__((ext_vector_type(4))) unsigned int u32x4;
typedef __attribute__((ext_vector_type(2))) unsigned int u32x2;

// workspace layout (bytes)
#define OFF_WH   0                              // 384*256 fp16 folded weights
#define OFF_BIAS (CT*CIN*2)                     // 384 fp32 folded bias
#define OFF_FEAT (OFF_BIAS + CT*4)              // [n][256][4096] fp16
#define OFF_Q    (OFF_FEAT + NB*CF*HWX*2)       // [n][4096][128] fp16
#define OFF_NORM (OFF_Q + NB*HWX*CA*2)          // [n][4096] fp32 row norms of q
#define OFF_G    (OFF_NORM + NB*HWX*4)          // [n] uint (max norm bits)

__device__ inline unsigned short f16_bits(float f) {
  _Float16 h = (_Float16)f;
  return __builtin_bit_cast(unsigned short, h);
}
__device__ inline half8 ld_half8(const unsigned short* p) {
  short8 r = *(const short8*)p;
  return __builtin_bit_cast(half8, r);
}

// async global->LDS, 16B per lane; LDS side must be lane-linear (m104/m108),
// swizzle goes on the GLOBAL address.
__device__ inline void g2l16(const void* g, void* l) {
  __builtin_amdgcn_global_load_lds(
      (const __attribute__((address_space(1))) unsigned int*)g,
      (__attribute__((address_space(3))) unsigned int*)l, 16, 0, 0);
}

// ---------------- kernel 1: fold BN into fp16 weights (+ zero G) ----------------
__global__ __launch_bounds__(256) void fold_bn_k(
    const float* __restrict__ rw, const float* __restrict__ rg,
    const float* __restrict__ rb, const float* __restrict__ rm, const float* __restrict__ rv,
    const float* __restrict__ aw, const float* __restrict__ ag,
    const float* __restrict__ ab2, const float* __restrict__ am, const float* __restrict__ av,
    unsigned short* __restrict__ wh, float* __restrict__ bias, unsigned* __restrict__ Gmax) {
  int o = blockIdx.x, k = threadIdx.x;
  if (o == 0 && k < NB) Gmax[k] = 0u;
  const float* wsrc; float g, b, m, v;
  if (o < CF) { wsrc = rw + (size_t)o*CIN; g = rg[o]; b = rb[o]; m = rm[o]; v = rv[o]; }
  else { int oa = o - CF; wsrc = aw + (size_t)oa*CIN; g = ag[oa]; b = ab2[oa]; m = am[oa]; v = av[oa]; }
  float inv = g / sqrtf(v + 1e-5f);
  wh[(size_t)o*CIN + k] = f16_bits(wsrc[k] * inv);
  if (k == 0) bias[o] = b - m*inv;
}

// ---------------- kernel 2: fp16 MFMA conv(1x1)+BN+ReLU ----------------
// grid 512 = 8n x 64 pos-tiles(64); 512 thr (8 waves); 2 blocks/CU.
// Block tile: [64 pos] x [384 oc] x K=256. Wave w owns oc slab [w*48, w*48+48).
// sX is XOR-unit-swizzled (unit = 16B): conflict-free staging writes AND A-frag reads
// (the old stride-264 layout had 8-way conflicts on both -- the conv's hidden cost).
__global__ __launch_bounds__(512, 4) void conv_k(
    const float* __restrict__ x, const unsigned short* __restrict__ wh,
    const float* __restrict__ bias, unsigned short* __restrict__ feat,
    unsigned short* __restrict__ q, float* __restrict__ normq,
    unsigned* __restrict__ Gmax) {
  __shared__ unsigned short sX[64*256];   // xT [64 pos][256 k] fp16, swizzled; 32KB
  unsigned short (*sQr)[136] = (unsigned short(*)[136])sX;  // aliased after K-loop
  int b = blockIdx.x;
  int n = b & 7, pt0 = b >> 3;
  int p0 = pt0 * 64;
  int t = threadIdx.x;
  int w = t >> 6, lane = t & 63, quad = lane >> 4, col = lane & 15;
  const float* xn = x + (size_t)n*CIN*HWX;

  // stage x tile [256 k][64 pos] -> sX transposed fp16, swizzled.
  // thread: kp = k-pair, c4 = f32x4 pos group; 256B contiguous per k-row per block.
  #pragma unroll
  for (int pass=0; pass<4; pass++) {
    int idx = pass*512 + t;
    int kp = idx >> 4, c4 = idx & 15;
    f32x4 a = *(const f32x4*)(xn + (size_t)(2*kp)*HWX + p0 + c4*4);
    f32x4 c = *(const f32x4*)(xn + (size_t)(2*kp+1)*HWX + p0 + c4*4);
    int unit = kp >> 2, off = kp & 3;
    #pragma unroll
    for (int j=0;j<4;j++) {
      int pos = c4*4 + j;
      unsigned dd = (unsigned)f16_bits(a[j]) | ((unsigned)f16_bits(c[j]) << 16);
      *(unsigned*)&sX[pos*256 + ((unit ^ (pos & 31)) << 3) + off*2] = dd;
    }
  }
  __syncthreads();

  f32x4 fzero = {0.f,0.f,0.f,0.f};
  f32x4 acc[4][3];                  // [pos-tile][oc-tile]
  #pragma unroll
  for (int pt=0;pt<4;pt++)
    #pragma unroll
    for (int ot=0;ot<3;ot++) acc[pt][ot] = fzero;

  int ocb = w*48;
  #pragma unroll
  for (int ks=0; ks<8; ks++) {
    half8 B3[3];
    #pragma unroll
    for (int ot=0;ot<3;ot++)
      B3[ot] = ld_half8(wh + (size_t)(ocb + ot*16 + col)*CIN + ks*32 + quad*8);
    half8 A4[4];
    #pragma unroll
    for (int pt=0;pt<4;pt++) {
      int pos = pt*16 + col;
      A4[pt] = ld_half8(&sX[pos*256 + (((ks*4 + quad) ^ (pos & 31)) << 3)]);
    }
    #pragma unroll
    for (int pt=0;pt<4;pt++)
      #pragma unroll
      for (int ot=0;ot<3;ot++)
        acc[pt][ot] = __builtin_amdgcn_mfma_f32_16x16x32_f16(A4[pt], B3[ot], acc[pt][ot], 0, 0, 0);
  }
  __syncthreads();   // all sX reads done; region reused as sQr

  // epilogue: bias+ReLU; feat (oc<256) direct 8B stores; q (oc>=256) via LDS transpose
  float bv[3];
  #pragma unroll
  for (int ot=0;ot<3;ot++) bv[ot] = bias[ocb + ot*16 + col];
  #pragma unroll
  for (int pt=0;pt<4;pt++)
    #pragma unroll
    for (int ot=0;ot<3;ot++) {
      int oc = ocb + ot*16 + col;
      alignas(8) unsigned short u4[4];
      #pragma unroll
      for (int r=0;r<4;r++)
        u4[r] = f16_bits(fmaxf(acc[pt][ot][r] + bv[ot], 0.f));
      if (oc < CF) {
        *(u32x2*)(feat + (size_t)n*CF*HWX + (size_t)oc*HWX + p0 + pt*16 + quad*4) =
            *(const u32x2*)u4;
      } else {
        int cc = oc - CF;
        #pragma unroll
        for (int r=0;r<4;r++)
          sQr[pt*16 + quad*4 + r][cc] = u4[r];
      }
    }
  __syncthreads();

  // q readback + row norms: t<256: pos = t>>2 (64), seg = t&3 (32 c each)
  if (t < 256) {
    int pos = t >> 2, seg = t & 3;
    const unsigned short* src = &sQr[pos][seg*32];
    unsigned short* dst = q + ((size_t)n*HWX + p0 + pos)*CA + seg*32;
    float s2 = 0.f;
    #pragma unroll
    for (int u=0;u<4;u++) {
      short8 v = *(const short8*)(src + u*8);
      *(short8*)(dst + u*8) = v;
      half8 h = __builtin_bit_cast(half8, v);
      #pragma unroll
      for (int e=0;e<8;e++) { float fe = (float)h[e]; s2 += fe*fe; }
    }
    s2 += __shfl_xor(s2, 1, 64);
    s2 += __shfl_xor(s2, 2, 64);
    if (seg == 0) normq[(size_t)n*HWX + p0 + pos] = sqrtf(s2);
    float mx = s2;
    mx = fmaxf(mx, __shfl_xor(mx, 4, 64));
    mx = fmaxf(mx, __shfl_xor(mx, 8, 64));
    mx = fmaxf(mx, __shfl_xor(mx, 16, 64));
    mx = fmaxf(mx, __shfl_xor(mx, 32, 64));
    if (lane == 0) atomicMax(Gmax + n, __float_as_uint(sqrtf(mx)));
  }
}

// ---------------- kernel 3: flash attention, BN=128, two barriers/iter ----------------
// grid 512 = 8n x 64 i-tiles (BM=64); 512 thr (8 waves), 2 blocks/CU, 4 waves/SIMD.
// Wave (wq=w&3, wh=w>>2): QK computes S[wq rows 16][wh j-half 64] = 16 MFMA as 4
// independent depth-4 chains; PV owns c-slab w*32 for all 64 i = 32 MFMA as 8 chains.
// Single-buffered sQ (32KB) / sP (pad 136 -> ~2-way aP reads); 32 iters -> half the
// barriers of R5. Max-free softmax via per-row Cauchy-Schwarz bound.
__global__ __launch_bounds__(512, 4) void flash_k(
    const unsigned short* __restrict__ q, const unsigned short* __restrict__ feat,
    const float* __restrict__ mask, const float* __restrict__ normq,
    const unsigned* __restrict__ Gmax, float* __restrict__ out) {
  __shared__ alignas(16) unsigned short sQ[128*128];  // j-tile q fp16, octet-swizzled
  __shared__ alignas(16) unsigned short sP[64][136];  // P (A-layout), pad 136
  __shared__ float sM[128];
  __shared__ float sL[2][64];
  int b = blockIdx.x;
  int n = b & 7, it = b >> 3;         // n == XCD for L2 locality
  int i0 = it * 64;
  int t = threadIdx.x;
  int w = t >> 6, lane = t & 63, quad = lane >> 4, col = lane & 15;
  int wq = w & 3, wh = w >> 2;
  const unsigned short* q_n = q + (size_t)n*HWX*CA;
  const unsigned short* f_n = feat + (size_t)n*CF*HWX;
  const float* m_n = mask + (size_t)n*HWX;
  const int rloc = t >> 4 & 31, oct16 = t & 15;
  const float inv_s = 1.0f/(1e-8f + sqrtf(128.0f));

  auto stage_Q = [&](int j0) {
    #pragma unroll
    for (int c=0;c<4;c++) {
      int row = c*32 + rloc;
      int og = oct16 ^ (row & 15);
      g2l16(q_n + (size_t)(j0+row)*CA + og*8, &sQ[(size_t)row*128 + oct16*8]);
    }
    if (t < 32) g2l16(m_n + j0 + t*4, &sM[t*4]);
  };

  // A fragments for QK (this wave's 16 i rows)
  half8 ah[4];
  {
    int arow = i0 + wq*16 + col;
    #pragma unroll
    for (int ks=0; ks<4; ks++)
      ah[ks] = ld_half8(q_n + (size_t)arow*CA + ks*32 + quad*8);
  }
  // per-row exp shift: C_i - 5
  float Gn = __uint_as_float(Gmax[n]);
  float cvals[4];
  #pragma unroll
  for (int r=0;r<4;r++)
    cvals[r] = normq[(size_t)n*HWX + i0 + wq*16 + quad*4 + r] * Gn * inv_s - 5.0f;

  f32x4 fzero = {0.f,0.f,0.f,0.f};
  f32x4 o[4][2];                      // [i-group][c-tile], c-slab = w*32
  #pragma unroll
  for (int ig=0;ig<4;ig++) { o[ig][0] = fzero; o[ig][1] = fzero; }
  float lrun[4] = {0.f,0.f,0.f,0.f};

  stage_Q(0);
  #pragma unroll 1
  for (int ji = 0; ji < 32; ji++) {
    int j0 = ji*128;
    __syncthreads();                  // A: sQ(ji)+sM(ji) ready; PV(ji-1) done with sP

    // prefetch PV B-frags for ks2=0,1 (consumed after barrier B; L2 latency hides
    // under QK+softmax). ks2=2,3 loaded at PV start to cap live registers.
    half8 bF01[2][2];
    #pragma unroll
    for (int ks2=0;ks2<2;ks2++)
      #pragma unroll
      for (int ct=0;ct<2;ct++) {
        int c = w*32 + ct*16 + col;
        bF01[ks2][ct] = ld_half8(f_n + (size_t)c*HWX + j0 + ks2*32 + quad*8);
      }

    // ---- QK^T: S[16 i x 64 j] (this wave's j-half), 4 indep chains of 4
    f32x4 s[4];
    #pragma unroll
    for (int jt=0;jt<4;jt++) s[jt] = fzero;
    #pragma unroll
    for (int jt=0;jt<4;jt++) {
      int rowj = wh*64 + jt*16 + col;
      #pragma unroll
      for (int ks=0; ks<4; ks++) {
        int slot = (ks*4 + quad) ^ (rowj & 15);
        half8 bq = ld_half8(&sQ[rowj*128 + slot*8]);
        s[jt] = __builtin_amdgcn_mfma_f32_16x16x32_f16(ah[ks], bq, s[jt], 0, 0, 0);
      }
    }

    // ---- max-free softmax: P = exp(E*inv_s + maskterm - C_i + 5); l += P
    #pragma unroll
    for (int jt=0;jt<4;jt++) {
      float mj = (sM[wh*64 + jt*16 + col] - 1.f) * 1e8f;
      #pragma unroll
      for (int r=0;r<4;r++) {
        float p = __expf(s[jt][r]*inv_s + mj - cvals[r]);
        lrun[r] += p;
        sP[wq*16 + quad*4 + r][wh*64 + jt*16 + col] = f16_bits(p);
      }
    }

    __syncthreads();                  // B: sP visible; QK reads of sQ done
    if (ji + 1 < 32) stage_Q(j0+128); // overlaps PV, drained at next barrier A

    // ---- PV: O[64 i x 32 c] for this wave's c-slab, K=128
    half8 bF23[2][2];
    #pragma unroll
    for (int ks2=0;ks2<2;ks2++)
      #pragma unroll
      for (int ct=0;ct<2;ct++) {
        int c = w*32 + ct*16 + col;
        bF23[ks2][ct] = ld_half8(f_n + (size_t)c*HWX + j0 + (ks2+2)*32 + quad*8);
      }
    #pragma unroll
    for (int ks2=0; ks2<4; ks2++) {
      half8 aP[4];
      #pragma unroll
      for (int ig=0;ig<4;ig++)
        aP[ig] = ld_half8(&sP[ig*16 + col][ks2*32 + quad*8]);
      #pragma unroll
      for (int ct=0;ct<2;ct++) {
        half8 bF = (ks2 < 2) ? bF01[ks2][ct] : bF23[ks2-2][ct];
        #pragma unroll
        for (int ig=0;ig<4;ig++)
          o[ig][ct] = __builtin_amdgcn_mfma_f32_16x16x32_f16(aP[ig], bF, o[ig][ct], 0, 0, 0);
      }
    }
  }

  // ---- final l: reduce 16 j-cols in-wave, combine halves via LDS
  #pragma unroll
  for (int r=0;r<4;r++) {
    float ss = lrun[r];
    ss += __shfl_xor(ss, 1, 64);
    ss += __shfl_xor(ss, 2, 64);
    ss += __shfl_xor(ss, 4, 64);
    ss += __shfl_xor(ss, 8, 64);
    lrun[r] = ss;
  }
  #pragma unroll
  for (int r=0;r<4;r++)
    if (col == 0) sL[wh][wq*16 + quad*4 + r] = lrun[r];
  __syncthreads();
  #pragma unroll
  for (int ig=0;ig<4;ig++) {
    int base = ig*16 + quad*4;
    f32x4 l0 = *(const f32x4*)&sL[0][base];
    f32x4 l1 = *(const f32x4*)&sL[1][base];
    f32x4 mv = *(const f32x4*)(m_n + i0 + base);
    f32x4 minv;
    #pragma unroll
    for (int r=0;r<4;r++) minv[r] = mv[r] / (l0[r] + l1[r]);
    #pragma unroll
    for (int ct=0;ct<2;ct++) {
      int c = w*32 + ct*16 + col;
      f32x4 v;
      #pragma unroll
      for (int r=0;r<4;r++) v[r] = o[ig][ct][r] * minv[r];
      *(f32x4*)(out + ((size_t)n*CF + c)*HWX + i0 + base) = v;
    }
  }
}

extern "C" void kernel_launch(void* const* d_in, const int* in_sizes, int n_in,
                              void* d_out, int out_size, void* d_ws, size_t ws_size,
                              hipStream_t stream) {
  const float* x    = (const float*)d_in[0];
  const float* mask = (const float*)d_in[1];
  const float* rw   = (const float*)d_in[2];
  const float* rg   = (const float*)d_in[3];
  const float* rb   = (const float*)d_in[4];
  const float* rm   = (const float*)d_in[5];
  const float* rv   = (const float*)d_in[6];
  const float* aw   = (const float*)d_in[7];
  const float* ag   = (const float*)d_in[8];
  const float* ab   = (const float*)d_in[9];
  const float* am   = (const float*)d_in[10];
  const float* av   = (const float*)d_in[11];
  float* out = (float*)d_out;
  char* ws = (char*)d_ws;
  unsigned short* wh = (unsigned short*)(ws + OFF_WH);
  float* bias = (float*)(ws + OFF_BIAS);
  unsigned short* feat = (unsigned short*)(ws + OFF_FEAT);
  unsigned short* q    = (unsigned short*)(ws + OFF_Q);
  float* normq = (float*)(ws + OFF_NORM);
  unsigned* Gmax = (unsigned*)(ws + OFF_G);

  hipLaunchKernelGGL(fold_bn_k, dim3(CT), dim3(CIN), 0, stream,
                     rw, rg, rb, rm, rv, aw, ag, ab, am, av, wh, bias, Gmax);
  hipLaunchKernelGGL(conv_k, dim3(512), dim3(512), 0, stream,
                     x, wh, bias, feat, q, normq, Gmax);
  hipLaunchKernelGGL(flash_k, dim3(512), dim3(512), 0, stream,
                     q, feat, mask, normq, Gmax, out);
}